// Round 5
// baseline (307.460 us; speedup 1.0000x reference)
//
#include <hip/hip_runtime.h>
#include <math.h>

#define BB 32
#define DD 64
#define LL 8192
#define KK 512
#define NN (BB*LL)                 // 262144 rows

#define OUT0_SZ  (BB*DD*LL)        // 16777216
#define LOSS_OFF (OUT0_SZ)
#define PERP_OFF (OUT0_SZ + 1)
#define W_OFF    (OUT0_SZ + 2)
#define IDX_OFF  (W_OFF + KK*DD)   // 16809986

// ws float-offsets: tvec[512] | hist[512] | lacc | pad | wpack_h (32768 u16) | wpack_l
#define WS_TVEC 0
#define WS_HIST 512
#define WS_LACC 1024
#define WS_WPH  1032
#define WS_WPL  (1032 + 16384)
// needs ws_size >= ~135 KB (same as verified R2)

typedef __attribute__((ext_vector_type(4))) float f32x4;
typedef __attribute__((ext_vector_type(8))) short s16x8;
typedef unsigned long long u64;

#define WINDOW 1e-4f   // >> apx error (~1e-5); candidate-window logic verified in R2

__device__ __forceinline__ unsigned short f2bf(float f) {   // RNE f32->bf16
  unsigned int u = __float_as_uint(f);
  return (unsigned short)((u + 0x7FFFu + ((u >> 16) & 1u)) >> 16);
}
__device__ __forceinline__ float bf2f(unsigned short s) {
  return __uint_as_float(((unsigned int)s) << 16);
}
__device__ __forceinline__ u64 shflx64(u64 v, int m) {
  unsigned lo = __shfl_xor((unsigned)v, m);
  unsigned hi = __shfl_xor((unsigned)(v >> 32), m);
  return ((u64)hi << 32) | lo;
}

// -----------------------------------------------------------------------------
// init (32768 threads): exact t_k (np-pairwise), zero hist/lacc, pack codebook
// bf16 hi/lo in MFMA B-fragment order (verified R2), w passthrough.
__global__ void vq_init(const float* __restrict__ w, float* __restrict__ ws,
                        float* __restrict__ dout) {
#pragma clang fp contract(off)
  int t = blockIdx.x * blockDim.x + threadIdx.x;
  if (t < KK) {
    const float* wr = w + t * DD;
    float r[8];
#pragma unroll
    for (int j = 0; j < 8; j++) { float v = wr[j]; r[j] = v * v; }
#pragma unroll
    for (int blk = 8; blk < 64; blk += 8) {
#pragma unroll
      for (int j = 0; j < 8; j++) { float v = wr[blk + j]; float a = v * v; r[j] = r[j] + a; }
    }
    ws[WS_TVEC + t] = ((r[0] + r[1]) + (r[2] + r[3])) + ((r[4] + r[5]) + (r[6] + r[7]));
    ((int*)ws)[WS_HIST + t] = 0;
  }
  if (t == 0) ws[WS_LACC] = 0.0f;

  // codebook pack: B elem (k,n) -> lane = n + 16*(k/8), j = k%8
  {
    int j    = t & 7;
    int lane = (t >> 3) & 63;
    int ks   = (t >> 9) & 1;
    int ct   = t >> 10;
    int code = ct * 16 + (lane & 15);
    int d    = ks * 32 + ((lane >> 4) << 3) + j;
    float v  = w[code * DD + d];
    unsigned short h = f2bf(v);
    unsigned short l = f2bf(v - bf2f(h));
    ((unsigned short*)(ws + WS_WPH))[((ct * 2 + ks) * 64 + lane) * 8 + j] = h;
    ((unsigned short*)(ws + WS_WPL))[((ct * 2 + ks) * 64 + lane) * 8 + j] = l;
  }

  // weight passthrough (W_OFF 8B-aligned -> float2)
  if (t < KK * DD / 2) {
    ((float2*)(dout + W_OFF))[t] = ((const float2*)w)[t];
  }
}

// -----------------------------------------------------------------------------
// main: 2048 blocks x 256 threads. Wave owns 32 rows (2 MFMA row-tiles);
// 2 lanes per row (lane r: d0-31, lane r+32: d32-63). Barriers only at the
// one-time phase boundaries; the 512-code loop is barrier-free.
__launch_bounds__(256, 2)
__global__ void vq_main(const float* __restrict__ x, const float* __restrict__ w,
                        const float* __restrict__ ws, float* __restrict__ dout) {
#pragma clang fp contract(off)
  __shared__ uint4 xstage[4][32][8];        // 16 KB: per-wave 32 rows x 32 u32 (pair-packed bf16)
  __shared__ float t_lds[KK];               // 2 KB
  __shared__ float s_lds[128];              // 512 B
  __shared__ u64   g_lds[128];              // 1 KB
  __shared__ unsigned short cand[128][4];   // 1 KB
  __shared__ int   ccnt[128];               // 512 B
  __shared__ unsigned char flags[KK];       // 512 B

  const float* tvec = ws + WS_TVEC;
  const s16x8* wph8 = (const s16x8*)(ws + WS_WPH);
  const s16x8* wpl8 = (const s16x8*)(ws + WS_WPL);
  int* hist = (int*)ws + WS_HIST;
  float* lacc = (float*)ws + WS_LACC;

  const int tid  = threadIdx.x;
  const int lane = tid & 63;
  const int wv   = tid >> 6;
  const int rloc = lane & 31;       // wave-local row
  const int half = lane >> 5;       // 0: d0-31, 1: d32-63
  const int res  = lane & 15;       // code residue this lane tracks

  for (int e = tid; e < KK; e += 256) { t_lds[e] = tvec[e]; flags[e] = 0; }
  if (tid < 128) ccnt[tid] = 0;

  const int n = blockIdx.x * 128 + wv * 32 + rloc;
  const int b = n >> 13, l = n & 8191;
  const float* px = x + (size_t)b * DD * LL + l;

  // this lane's 32 d-values
  float xh[32];
#pragma unroll
  for (int i = 0; i < 32; i++) xh[i] = px[(size_t)(half * 32 + i) * LL];

  // apx s = ||x||^2 (half-sums combined; uniform per-row shift -> argmin/window-safe:
  // s is constant across k within a row, so any s rounding cancels in comparisons)
  float s_apx;
  {
    float r[8];
#pragma unroll
    for (int j = 0; j < 8; j++) r[j] = xh[j] * xh[j];
#pragma unroll
    for (int blk = 8; blk < 32; blk += 8) {
#pragma unroll
      for (int j = 0; j < 8; j++) { float a = xh[blk + j] * xh[blk + j]; r[j] = r[j] + a; }
    }
    float sh = ((r[0] + r[1]) + (r[2] + r[3])) + ((r[4] + r[5]) + (r[6] + r[7]));
    float so = __shfl(sh, lane ^ 32);
    float slo = half ? so : sh, shi = half ? sh : so;
    s_apx = slo + shi;              // same bits in both partner lanes
    if (half == 0) s_lds[wv * 32 + rloc] = s_apx;
  }

  // ---- staging, hi then lo, swizzled uint4 (bank-minimal both directions) ----
  uint4* xs4 = (uint4*)xstage;
  const s16x8* xs8 = (const s16x8*)xstage;
  s16x8 afh[2][2], afl[2][2];
  {
    unsigned int pk[16];
#pragma unroll
    for (int m = 0; m < 16; m++)
      pk[m] = (unsigned int)f2bf(xh[2 * m]) | ((unsigned int)f2bf(xh[2 * m + 1]) << 16);
#pragma unroll
    for (int q = 0; q < 4; q++) {
      int sw = (half * 4 + q) ^ (rloc & 7);
      uint4 v; v.x = pk[4 * q]; v.y = pk[4 * q + 1]; v.z = pk[4 * q + 2]; v.w = pk[4 * q + 3];
      xs4[(wv * 32 + rloc) * 8 + sw] = v;
    }
    __syncthreads();   // barrier #1: shared-init + s_lds + hi stage visible
#pragma unroll
    for (int t2 = 0; t2 < 2; t2++)
#pragma unroll
      for (int ks = 0; ks < 2; ks++) {
        int row = t2 * 16 + (lane & 15);
        int sw = (ks * 4 + (lane >> 4)) ^ (lane & 7);
        afh[t2][ks] = xs8[(wv * 32 + row) * 8 + sw];
      }
    __syncthreads();   // barrier #2: hi reads complete before lo overwrite
    // lo pass (residuals), same buffer
#pragma unroll
    for (int m = 0; m < 16; m++) {
      float v0 = xh[2 * m],     h0 = bf2f(f2bf(v0));
      float v1 = xh[2 * m + 1], h1 = bf2f(f2bf(v1));
      pk[m] = (unsigned int)f2bf(v0 - h0) | ((unsigned int)f2bf(v1 - h1) << 16);
    }
#pragma unroll
    for (int q = 0; q < 4; q++) {
      int sw = (half * 4 + q) ^ (rloc & 7);
      uint4 v; v.x = pk[4 * q]; v.y = pk[4 * q + 1]; v.z = pk[4 * q + 2]; v.w = pk[4 * q + 3];
      xs4[(wv * 32 + rloc) * 8 + sw] = v;
    }
    __syncthreads();   // barrier #3: lo staged
#pragma unroll
    for (int t2 = 0; t2 < 2; t2++)
#pragma unroll
      for (int ks = 0; ks < 2; ks++) {
        int row = t2 * 16 + (lane & 15);
        int sw = (ks * 4 + (lane >> 4)) ^ (lane & 7);
        afl[t2][ks] = xs8[(wv * 32 + row) * 8 + sw];
      }
  }

  // s-fragments: acc row within tile = (lane>>4)*4 + r
  float sfr[2][4];
#pragma unroll
  for (int t2 = 0; t2 < 2; t2++)
#pragma unroll
    for (int r = 0; r < 4; r++)
      sfr[t2][r] = s_lds[wv * 32 + t2 * 16 + ((lane >> 4) << 2) + r];

  float d1[2][4], d2[2][4]; int k1[2][4];
#pragma unroll
  for (int t2 = 0; t2 < 2; t2++)
#pragma unroll
    for (int r = 0; r < 4; r++) { d1[t2][r] = INFINITY; d2[t2][r] = INFINITY; k1[t2][r] = 0; }

  // B prefetch (double-buffer one ct ahead)
  s16x8 bh0 = wph8[lane], bh1 = wph8[64 + lane];
  s16x8 bl0 = wpl8[lane], bl1 = wpl8[64 + lane];
  float tc = t_lds[res];

#pragma clang loop unroll(disable)
  for (int ct = 0; ct < 32; ct++) {
    int cn = (ct + 1) & 31;   // wrap: harmless re-read
    s16x8 nh0 = wph8[cn * 128 + lane],      nh1 = wph8[cn * 128 + 64 + lane];
    s16x8 nl0 = wpl8[cn * 128 + lane],      nl1 = wpl8[cn * 128 + 64 + lane];
    float ntc = t_lds[cn * 16 + res];

#pragma unroll
    for (int t2 = 0; t2 < 2; t2++) {
      f32x4 acc = {0.f, 0.f, 0.f, 0.f};
      acc = __builtin_amdgcn_mfma_f32_16x16x32_bf16(afl[t2][0], bh0, acc, 0, 0, 0);
      acc = __builtin_amdgcn_mfma_f32_16x16x32_bf16(afl[t2][1], bh1, acc, 0, 0, 0);
      acc = __builtin_amdgcn_mfma_f32_16x16x32_bf16(afh[t2][0], bl0, acc, 0, 0, 0);
      acc = __builtin_amdgcn_mfma_f32_16x16x32_bf16(afh[t2][1], bl1, acc, 0, 0, 0);
      acc = __builtin_amdgcn_mfma_f32_16x16x32_bf16(afh[t2][0], bh0, acc, 0, 0, 0);
      acc = __builtin_amdgcn_mfma_f32_16x16x32_bf16(afh[t2][1], bh1, acc, 0, 0, 0);
#pragma unroll
      for (int r = 0; r < 4; r++) {
        float u = sfr[t2][r] + tc;
        float dap = fmaf(-2.0f, acc[r], u);
        bool c1 = dap < d1[t2][r];
        bool c2 = dap < d2[t2][r];
        d2[t2][r] = c1 ? d1[t2][r] : (c2 ? dap : d2[t2][r]);
        d1[t2][r] = c1 ? dap : d1[t2][r];
        k1[t2][r] = c1 ? ct : k1[t2][r];
      }
    }
    bh0 = nh0; bh1 = nh1; bl0 = nl0; bl1 = nl1; tc = ntc;
  }

  // ---- per-row global min (u64 butterfly over the 16 residue lanes) ----
  u64 gmin[2][4];
#pragma unroll
  for (int t2 = 0; t2 < 2; t2++)
#pragma unroll
    for (int r = 0; r < 4; r++) {
      u64 pk = (((u64)__float_as_uint(d1[t2][r])) << 32) | (u64)(k1[t2][r] * 16 + res);
      u64 q1 = shflx64(pk, 1); pk = pk < q1 ? pk : q1;
      u64 q2 = shflx64(pk, 2); pk = pk < q2 ? pk : q2;
      u64 q4 = shflx64(pk, 4); pk = pk < q4 ? pk : q4;
      u64 q8 = shflx64(pk, 8); pk = pk < q8 ? pk : q8;
      gmin[t2][r] = pk;
    }

  // window collection (block-local LDS; rows are wave-owned so no cross-wave mixing)
#pragma unroll
  for (int t2 = 0; t2 < 2; t2++)
#pragma unroll
    for (int r = 0; r < 4; r++) {
      int row = wv * 32 + t2 * 16 + ((lane >> 4) << 2) + r;
      if (res == 0) g_lds[row] = gmin[t2][r];
      float thr = __uint_as_float((unsigned)(gmin[t2][r] >> 32)) + WINDOW;
      bool in1 = d1[t2][r] <= thr;
      bool in2 = d2[t2][r] <= thr;
      if (in1) { int p = atomicAdd(&ccnt[row], 1); if (p < 4) cand[row][p] = (unsigned short)(k1[t2][r] * 16 + res); }
      if (in2) { int p = atomicAdd(&ccnt[row], 1); if (p < 4) cand[row][p] = (unsigned short)(512 + res); }
    }
  __syncthreads();   // barrier #4: collection visible

  // ---- owner decision (lanes 0-31; 1 row each) ----
  int kwin = 0;
  if (lane < 32) {
    int row = wv * 32 + lane;
    int cnt = ccnt[row];
    if (cnt <= 1) {
      kwin = (int)(g_lds[row] & 0x1FFu);
    } else {
      // exact rescue, bit-identical chains to ref: reload upper half, exact s
      float xu[32];
#pragma unroll
      for (int i = 0; i < 32; i++) xu[i] = px[(size_t)(32 + i) * LL];
      float s;
      {
        float r[8];
#pragma unroll
        for (int j = 0; j < 8; j++) r[j] = xh[j] * xh[j];
#pragma unroll
        for (int blk = 8; blk < 32; blk += 8)
#pragma unroll
          for (int j = 0; j < 8; j++) { float a = xh[blk + j] * xh[blk + j]; r[j] = r[j] + a; }
#pragma unroll
        for (int blk = 0; blk < 32; blk += 8)
#pragma unroll
          for (int j = 0; j < 8; j++) { float a = xu[blk + j] * xu[blk + j]; r[j] = r[j] + a; }
        s = ((r[0] + r[1]) + (r[2] + r[3])) + ((r[4] + r[5]) + (r[6] + r[7]));
      }
      u64 best = ~0ULL;
      auto evalExact = [&](int c) {
        const float4* wr = (const float4*)(w + c * DD);
        float gg = 0.0f;
#pragma unroll
        for (int i = 0; i < 8; i++) {
          float4 wq = wr[i];
          gg = fmaf(xh[4 * i + 0], wq.x, gg); gg = fmaf(xh[4 * i + 1], wq.y, gg);
          gg = fmaf(xh[4 * i + 2], wq.z, gg); gg = fmaf(xh[4 * i + 3], wq.w, gg);
        }
#pragma unroll
        for (int i = 0; i < 8; i++) {
          float4 wq = wr[8 + i];
          gg = fmaf(xu[4 * i + 0], wq.x, gg); gg = fmaf(xu[4 * i + 1], wq.y, gg);
          gg = fmaf(xu[4 * i + 2], wq.z, gg); gg = fmaf(xu[4 * i + 3], wq.w, gg);
        }
        float de = fmaf(-2.0f, gg, s + t_lds[c]);
        u64 pk = (((u64)__float_as_uint(de)) << 32) | (u64)c;
        if (pk < best) best = pk;
      };
      if (cnt > 4) {
        for (int c = 0; c < KK; c++) evalExact(c);
      } else {
        for (int i = 0; i < cnt; i++) {
          int c = cand[row][i];
          if (c < 512) evalExact(c);
          else { int c0 = c - 512; for (int jj = 0; jj < 32; jj++) evalExact(jj * 16 + c0); }
        }
      }
      kwin = (int)(best & 0x1FFu);   // masked: logic bug => wrong answer, never OOB
    }
  }
  kwin = __shfl(kwin, lane & 31);    // broadcast to partner lane

  // ---- epilogue: output (transposed), loss, idx, flags ----
  float ls = 0.0f;
  {
    const float4* wr = (const float4*)(w + kwin * DD) + half * 8;
    float* o = dout + (size_t)b * DD * LL + l + (size_t)half * 32 * LL;
#pragma unroll
    for (int i = 0; i < 8; i++) {
      float4 v = wr[i];
      o[(size_t)(4 * i + 0) * LL] = v.x; o[(size_t)(4 * i + 1) * LL] = v.y;
      o[(size_t)(4 * i + 2) * LL] = v.z; o[(size_t)(4 * i + 3) * LL] = v.w;
      float df;
      df = v.x - xh[4 * i + 0]; ls = fmaf(df, df, ls);
      df = v.y - xh[4 * i + 1]; ls = fmaf(df, df, ls);
      df = v.z - xh[4 * i + 2]; ls = fmaf(df, df, ls);
      df = v.w - xh[4 * i + 3]; ls = fmaf(df, df, ls);
    }
  }
  if (half == 0) {
    dout[IDX_OFF + n] = (float)kwin;
    flags[kwin] = 1;
  }

  // loss: wave reduce then one atomic per wave (order-insensitive at tolerance)
#pragma unroll
  for (int o = 32; o > 0; o >>= 1) ls += __shfl_down(ls, o);
  if ((tid & 63) == 0) atomicAdd(lacc, ls);

  __syncthreads();   // barrier #5: flags complete
  for (int e = tid; e < KK; e += 256)
    if (flags[e]) atomicOr(&hist[e], 1);
}

// -----------------------------------------------------------------------------
// final: perplexity count + loss scalar (w passthrough in vq_init)
__global__ void vq_final(const float* __restrict__ ws, float* __restrict__ dout) {
  __shared__ int red[512];
  const int* hist = (const int*)ws + WS_HIST;
  int tid = threadIdx.x;
  red[tid] = (hist[tid] != 0) ? 1 : 0;
  __syncthreads();
  for (int sx = 256; sx > 0; sx >>= 1) {
    if (tid < sx) red[tid] += red[tid + sx];
    __syncthreads();
  }
  if (tid == 0) {
    dout[PERP_OFF] = (float)red[0];
    float m = ws[WS_LACC] / 16777216.0f;
    dout[LOSS_OFF] = m + 0.1f * m;   // q + 0.1*e with q==e numerically
  }
}

extern "C" void kernel_launch(void* const* d_in, const int* in_sizes, int n_in,
                              void* d_out, int out_size, void* d_ws, size_t ws_size,
                              hipStream_t stream) {
  const float* x = (const float*)d_in[0];
  const float* w = (const float*)d_in[1];
  float* dout = (float*)d_out;
  float* ws = (float*)d_ws;

  vq_init<<<128, 256, 0, stream>>>(w, ws, dout);
  vq_main<<<NN / 128, 256, 0, stream>>>(x, w, ws, dout);
  vq_final<<<1, 512, 0, stream>>>(ws, dout);
}

// Round 6
// 246.904 us; speedup vs baseline: 1.2453x; 1.2453x over previous
//
#include <hip/hip_runtime.h>
#include <math.h>

#define BB 32
#define DD 64
#define LL 8192
#define KK 512
#define NN (BB*LL)                 // 262144 rows

#define OUT0_SZ  (BB*DD*LL)        // 16777216
#define LOSS_OFF (OUT0_SZ)
#define PERP_OFF (OUT0_SZ + 1)
#define W_OFF    (OUT0_SZ + 2)
#define IDX_OFF  (W_OFF + KK*DD)   // 16809986

// ws float-offsets: tvec[512] | hist[512] | lacc | pad | wpack_h (32768 u16) | wpack_l
#define WS_TVEC 0
#define WS_HIST 512
#define WS_LACC 1024
#define WS_WPH  1032
#define WS_WPL  (1032 + 16384)
// needs ws_size >= ~135 KB (verified available in R2/R4)

typedef __attribute__((ext_vector_type(4))) float f32x4;
typedef __attribute__((ext_vector_type(8))) short s16x8;
typedef unsigned long long u64;

#define WINDOW 1e-4f   // >= 2*(apx err ~1e-6 + ref-chain ulp(64) wobble ~8e-6); verified logic R2/R4

__device__ __forceinline__ unsigned short f2bf(float f) {   // RNE f32->bf16
  unsigned int u = __float_as_uint(f);
  return (unsigned short)((u + 0x7FFFu + ((u >> 16) & 1u)) >> 16);
}
__device__ __forceinline__ float bf2f(unsigned short s) {
  return __uint_as_float(((unsigned int)s) << 16);
}
__device__ __forceinline__ u64 shflx64(u64 v, int m) {
  unsigned lo = __shfl_xor((unsigned)v, m);
  unsigned hi = __shfl_xor((unsigned)(v >> 32), m);
  return ((u64)hi << 32) | lo;
}
// order-preserving float<->uint (handles negative d' = t - 2g)
__device__ __forceinline__ unsigned fenc(float f) {
  unsigned u = __float_as_uint(f);
  return (u & 0x80000000u) ? ~u : (u | 0x80000000u);
}
__device__ __forceinline__ float fdec(unsigned e) {
  return __uint_as_float((e & 0x80000000u) ? (e ^ 0x80000000u) : ~e);
}

// -----------------------------------------------------------------------------
// init (32768 threads): exact t_k (np-pairwise), zero hist/lacc, pack codebook
// bf16 hi/lo in MFMA B-fragment order (verified R2/R4), w passthrough.
__global__ void vq_init(const float* __restrict__ w, float* __restrict__ ws,
                        float* __restrict__ dout) {
#pragma clang fp contract(off)
  int t = blockIdx.x * blockDim.x + threadIdx.x;
  if (t < KK) {
    const float* wr = w + t * DD;
    float r[8];
#pragma unroll
    for (int j = 0; j < 8; j++) { float v = wr[j]; r[j] = v * v; }
#pragma unroll
    for (int blk = 8; blk < 64; blk += 8) {
#pragma unroll
      for (int j = 0; j < 8; j++) { float v = wr[blk + j]; float a = v * v; r[j] = r[j] + a; }
    }
    ws[WS_TVEC + t] = ((r[0] + r[1]) + (r[2] + r[3])) + ((r[4] + r[5]) + (r[6] + r[7]));
    ((int*)ws)[WS_HIST + t] = 0;
  }
  if (t == 0) ws[WS_LACC] = 0.0f;

  // codebook pack: B elem (k,n) -> lane = n + 16*(k/8), j = k%8
  {
    int j    = t & 7;
    int lane = (t >> 3) & 63;
    int ks   = (t >> 9) & 1;
    int ct   = t >> 10;
    int code = ct * 16 + (lane & 15);
    int d    = ks * 32 + ((lane >> 4) << 3) + j;
    float v  = w[code * DD + d];
    unsigned short h = f2bf(v);
    unsigned short l = f2bf(v - bf2f(h));
    ((unsigned short*)(ws + WS_WPH))[((ct * 2 + ks) * 64 + lane) * 8 + j] = h;
    ((unsigned short*)(ws + WS_WPL))[((ct * 2 + ks) * 64 + lane) * 8 + j] = l;
  }

  // weight passthrough (W_OFF 8B-aligned -> float2)
  if (t < KK * DD / 2) {
    ((float2*)(dout + W_OFF))[t] = ((const float2*)w)[t];
  }
}

// -----------------------------------------------------------------------------
// main: 1024 blocks x 256 threads. Wave owns 64 rows (4 MFMA row-tiles), lane
// owns 1 row. s-less filter (d' = t - 2g): argmin/window shift-invariant;
// exact rescue recomputes the bit-matching s + t - 2g chain. x is NOT held in
// registers during the loop (reloaded from L3 in the epilogue). 1 pre-loop
// barrier; the 512-code loop is barrier-free.
__launch_bounds__(256, 2)
__global__ void vq_main(const float* __restrict__ x, const float* __restrict__ w,
                        const float* __restrict__ ws, float* __restrict__ dout) {
#pragma clang fp contract(off)
  __shared__ uint4 xh_lds[4][64][8];        // 32 KB bf16-hi, swizzled slots
  __shared__ uint4 xl_lds[4][64][8];        // 32 KB bf16-lo
  __shared__ float t_lds[KK];               // 2 KB
  __shared__ u64   g_lds[256];              // 2 KB
  __shared__ unsigned short cand[256][4];   // 2 KB
  __shared__ int   ccnt[256];               // 1 KB
  __shared__ unsigned char flags[KK];       // 512 B

  const float* tvec = ws + WS_TVEC;
  const s16x8* wph8 = (const s16x8*)(ws + WS_WPH);
  const s16x8* wpl8 = (const s16x8*)(ws + WS_WPL);
  int* hist = (int*)ws + WS_HIST;
  float* lacc = (float*)ws + WS_LACC;

  const int tid  = threadIdx.x;
  const int lane = tid & 63;
  const int wv   = tid >> 6;
  const int res  = lane & 15;       // code residue this lane tracks

  for (int e = tid; e < KK; e += 256) { t_lds[e] = tvec[e]; flags[e] = 0; }
  ccnt[tid] = 0;

  const int n = blockIdx.x * 256 + wv * 64 + lane;   // lane's row
  const int b = n >> 13, l = n & 8191;
  const float* px = x + (size_t)b * DD * LL + l;

  // ---- stage hi+lo bf16 into LDS (transient regs; x not kept) ----
  {
    float xv[64];
#pragma unroll
    for (int i = 0; i < 64; i++) xv[i] = px[(size_t)i * LL];
#pragma unroll
    for (int blk = 0; blk < 8; blk++) {
      unsigned ph[4], pl[4];
#pragma unroll
      for (int q = 0; q < 4; q++) {
        float v0 = xv[blk * 8 + 2 * q],     v1 = xv[blk * 8 + 2 * q + 1];
        unsigned short h0 = f2bf(v0), h1 = f2bf(v1);
        unsigned short l0 = f2bf(v0 - bf2f(h0)), l1 = f2bf(v1 - bf2f(h1));
        ph[q] = (unsigned)h0 | ((unsigned)h1 << 16);
        pl[q] = (unsigned)l0 | ((unsigned)l1 << 16);
      }
      int sw = blk ^ (lane & 7);          // conflict-free swizzle (R4-verified family)
      uint4 vh; vh.x = ph[0]; vh.y = ph[1]; vh.z = ph[2]; vh.w = ph[3];
      uint4 vl; vl.x = pl[0]; vl.y = pl[1]; vl.z = pl[2]; vl.w = pl[3];
      xh_lds[wv][lane][sw] = vh;
      xl_lds[wv][lane][sw] = vl;
    }
  }
  __syncthreads();   // barrier #1: t_lds, flags, ccnt, staging all visible

  // ---- A-fragments (verified mapping): row = t2*16+(lane&15), k = ks*32+8*(lane>>4)+j ----
  s16x8 afh[4][2], afl[4][2];
  {
    const s16x8* xh8 = (const s16x8*)xh_lds;
    const s16x8* xl8 = (const s16x8*)xl_lds;
#pragma unroll
    for (int t2 = 0; t2 < 4; t2++)
#pragma unroll
      for (int ks = 0; ks < 2; ks++) {
        int idx = (wv * 64 + t2 * 16 + (lane & 15)) * 8 + ((ks * 4 + (lane >> 4)) ^ (lane & 7));
        afh[t2][ks] = xh8[idx];
        afl[t2][ks] = xl8[idx];
      }
  }

  float d1[4][4], d2[4][4]; int k1[4][4];
#pragma unroll
  for (int t2 = 0; t2 < 4; t2++)
#pragma unroll
    for (int r = 0; r < 4; r++) { d1[t2][r] = INFINITY; d2[t2][r] = INFINITY; k1[t2][r] = 0; }

  // B prefetch (1-deep ring)
  s16x8 bh0 = wph8[lane], bh1 = wph8[64 + lane];
  s16x8 bl0 = wpl8[lane], bl1 = wpl8[64 + lane];
  float tc = t_lds[res];

#pragma clang loop unroll(disable)
  for (int ct = 0; ct < 32; ct++) {
    int cn = (ct + 1) & 31;   // wrap: harmless re-read
    s16x8 nh0 = wph8[cn * 128 + lane],      nh1 = wph8[cn * 128 + 64 + lane];
    s16x8 nl0 = wpl8[cn * 128 + lane],      nl1 = wpl8[cn * 128 + 64 + lane];
    float ntc = t_lds[cn * 16 + res];

#pragma unroll
    for (int t2 = 0; t2 < 4; t2++) {
      f32x4 acc = {0.f, 0.f, 0.f, 0.f};
      acc = __builtin_amdgcn_mfma_f32_16x16x32_bf16(afl[t2][0], bh0, acc, 0, 0, 0);
      acc = __builtin_amdgcn_mfma_f32_16x16x32_bf16(afl[t2][1], bh1, acc, 0, 0, 0);
      acc = __builtin_amdgcn_mfma_f32_16x16x32_bf16(afh[t2][0], bl0, acc, 0, 0, 0);
      acc = __builtin_amdgcn_mfma_f32_16x16x32_bf16(afh[t2][1], bl1, acc, 0, 0, 0);
      acc = __builtin_amdgcn_mfma_f32_16x16x32_bf16(afh[t2][0], bh0, acc, 0, 0, 0);
      acc = __builtin_amdgcn_mfma_f32_16x16x32_bf16(afh[t2][1], bh1, acc, 0, 0, 0);
#pragma unroll
      for (int r = 0; r < 4; r++) {
        float dap = fmaf(-2.0f, acc[r], tc);   // s-less: d' = t - 2g
        bool c1 = dap < d1[t2][r];
        bool c2 = dap < d2[t2][r];
        d2[t2][r] = c1 ? d1[t2][r] : (c2 ? dap : d2[t2][r]);
        d1[t2][r] = c1 ? dap : d1[t2][r];
        k1[t2][r] = c1 ? ct : k1[t2][r];
      }
    }
    bh0 = nh0; bh1 = nh1; bl0 = nl0; bl1 = nl1; tc = ntc;
  }

  // ---- per-row global min (order-preserving encode handles negative d') ----
  u64 gmin[4][4];
#pragma unroll
  for (int t2 = 0; t2 < 4; t2++)
#pragma unroll
    for (int r = 0; r < 4; r++) {
      u64 pk = (((u64)fenc(d1[t2][r])) << 32) | (u64)(k1[t2][r] * 16 + res);
      u64 q1 = shflx64(pk, 1); pk = pk < q1 ? pk : q1;
      u64 q2 = shflx64(pk, 2); pk = pk < q2 ? pk : q2;
      u64 q4 = shflx64(pk, 4); pk = pk < q4 ? pk : q4;
      u64 q8 = shflx64(pk, 8); pk = pk < q8 ? pk : q8;
      gmin[t2][r] = pk;
    }

  // window collection (rows wave-owned; LDS atomics)
#pragma unroll
  for (int t2 = 0; t2 < 4; t2++)
#pragma unroll
    for (int r = 0; r < 4; r++) {
      int row = wv * 64 + t2 * 16 + ((lane >> 4) << 2) + r;
      if (res == 0) g_lds[row] = gmin[t2][r];
      float thr = fdec((unsigned)(gmin[t2][r] >> 32)) + WINDOW;
      bool in1 = d1[t2][r] <= thr;
      bool in2 = d2[t2][r] <= thr;
      if (in1) { int p = atomicAdd(&ccnt[row], 1); if (p < 4) cand[row][p] = (unsigned short)(k1[t2][r] * 16 + res); }
      if (in2) { int p = atomicAdd(&ccnt[row], 1); if (p < 4) cand[row][p] = (unsigned short)(512 + res); }
    }
  __syncthreads();   // barrier #2: collection visible

  // ---- reload x (L3-resident) for loss/rescue ----
  float xr[64];
#pragma unroll
  for (int i = 0; i < 64; i++) xr[i] = px[(size_t)i * LL];

  // ---- owner decision (every lane owns its row) ----
  int kwin;
  {
    int row = wv * 64 + lane;
    int cnt = ccnt[row];
    if (cnt <= 1) {
      kwin = (int)(g_lds[row] & 0x1FFu);
    } else {
      // exact rescue: bit-identical chains to reference
      float s;
      {
        float r[8];
#pragma unroll
        for (int j = 0; j < 8; j++) r[j] = xr[j] * xr[j];
#pragma unroll
        for (int blk = 8; blk < 64; blk += 8)
#pragma unroll
          for (int j = 0; j < 8; j++) { float a = xr[blk + j] * xr[blk + j]; r[j] = r[j] + a; }
        s = ((r[0] + r[1]) + (r[2] + r[3])) + ((r[4] + r[5]) + (r[6] + r[7]));
      }
      u64 best = ~0ULL;
      auto evalExact = [&](int c) {
        const float4* wr = (const float4*)(w + c * DD);
        float gg = 0.0f;
#pragma unroll
        for (int i = 0; i < 16; i++) {
          float4 wq = wr[i];
          gg = fmaf(xr[4 * i + 0], wq.x, gg); gg = fmaf(xr[4 * i + 1], wq.y, gg);
          gg = fmaf(xr[4 * i + 2], wq.z, gg); gg = fmaf(xr[4 * i + 3], wq.w, gg);
        }
        float de = fmaf(-2.0f, gg, s + t_lds[c]);   // ref chain: fl(s+t) then fma
        u64 pk = (((u64)__float_as_uint(de)) << 32) | (u64)c;   // de>0: bit order ok
        if (pk < best) best = pk;
      };
      if (cnt > 4) {
        for (int c = 0; c < KK; c++) evalExact(c);
      } else {
        for (int i = 0; i < cnt; i++) {
          int c = cand[row][i];
          if (c < 512) evalExact(c);
          else { int c0 = c - 512; for (int jj = 0; jj < 32; jj++) evalExact(jj * 16 + c0); }
        }
      }
      kwin = (int)(best & 0x1FFu);   // masked: logic bug => wrong answer, never OOB
    }
  }

  // ---- epilogue: quantized output (transposed back), loss partial, idx, flags ----
  float ls = 0.0f;
  {
    float* o = dout + (size_t)b * DD * LL + l;
    const float4* wr = (const float4*)(w + kwin * DD);
#pragma unroll
    for (int i = 0; i < 16; i++) {
      float4 v = wr[i];
      o[(size_t)(4 * i + 0) * LL] = v.x; o[(size_t)(4 * i + 1) * LL] = v.y;
      o[(size_t)(4 * i + 2) * LL] = v.z; o[(size_t)(4 * i + 3) * LL] = v.w;
      float df;
      df = v.x - xr[4 * i + 0]; ls = fmaf(df, df, ls);
      df = v.y - xr[4 * i + 1]; ls = fmaf(df, df, ls);
      df = v.z - xr[4 * i + 2]; ls = fmaf(df, df, ls);
      df = v.w - xr[4 * i + 3]; ls = fmaf(df, df, ls);
    }
  }
  dout[IDX_OFF + n] = (float)kwin;
  flags[kwin] = 1;   // byte races benign (same value)

  // loss: wave reduce then one atomic per wave (order-insensitive at tolerance)
#pragma unroll
  for (int o = 32; o > 0; o >>= 1) ls += __shfl_down(ls, o);
  if ((tid & 63) == 0) atomicAdd(lacc, ls);

  __syncthreads();   // barrier #3: flags complete
  for (int e = tid; e < KK; e += 256)
    if (flags[e]) atomicOr(&hist[e], 1);
}

// -----------------------------------------------------------------------------
// final: perplexity count + loss scalar (w passthrough in vq_init)
__global__ void vq_final(const float* __restrict__ ws, float* __restrict__ dout) {
  __shared__ int red[512];
  const int* hist = (const int*)ws + WS_HIST;
  int tid = threadIdx.x;
  red[tid] = (hist[tid] != 0) ? 1 : 0;
  __syncthreads();
  for (int sx = 256; sx > 0; sx >>= 1) {
    if (tid < sx) red[tid] += red[tid + sx];
    __syncthreads();
  }
  if (tid == 0) {
    dout[PERP_OFF] = (float)red[0];
    float m = ws[WS_LACC] / 16777216.0f;
    dout[LOSS_OFF] = m + 0.1f * m;   // q + 0.1*e with q==e numerically
  }
}

extern "C" void kernel_launch(void* const* d_in, const int* in_sizes, int n_in,
                              void* d_out, int out_size, void* d_ws, size_t ws_size,
                              hipStream_t stream) {
  const float* x = (const float*)d_in[0];
  const float* w = (const float*)d_in[1];
  float* dout = (float*)d_out;
  float* ws = (float*)d_ws;

  vq_init<<<128, 256, 0, stream>>>(w, ws, dout);
  vq_main<<<NN / 256, 256, 0, stream>>>(x, w, ws, dout);
  vq_final<<<1, 512, 0, stream>>>(ws, dout);
}

// Round 7
// 236.754 us; speedup vs baseline: 1.2986x; 1.0429x over previous
//
#include <hip/hip_runtime.h>
#include <math.h>

#define BB 32
#define DD 64
#define LL 8192
#define KK 512
#define NN (BB*LL)                 // 262144 rows

#define OUT0_SZ  (BB*DD*LL)        // 16777216
#define LOSS_OFF (OUT0_SZ)
#define PERP_OFF (OUT0_SZ + 1)
#define W_OFF    (OUT0_SZ + 2)
#define IDX_OFF  (W_OFF + KK*DD)   // 16809986

// ws float-offsets: tvec[512] | hist[512] | lacc | pad | wpack_h (32768 u16) | wpack_l
#define WS_TVEC 0
#define WS_HIST 512
#define WS_LACC 1024
#define WS_WPH  1032
#define WS_WPL  (1032 + 16384)
// needs ws_size >= ~135 KB (verified available R2/R4/R5)

typedef __attribute__((ext_vector_type(4))) float f32x4;
typedef __attribute__((ext_vector_type(8))) short s16x8;
typedef unsigned long long u64;

#define WINDOW 1e-4f   // verified across R2/R4/R5 (3 passing rounds, idx all exact)

__device__ __forceinline__ unsigned short f2bf(float f) {   // RNE f32->bf16
  unsigned int u = __float_as_uint(f);
  return (unsigned short)((u + 0x7FFFu + ((u >> 16) & 1u)) >> 16);
}
__device__ __forceinline__ float bf2f(unsigned short s) {
  return __uint_as_float(((unsigned int)s) << 16);
}
__device__ __forceinline__ u64 shflx64(u64 v, int m) {
  unsigned lo = __shfl_xor((unsigned)v, m);
  unsigned hi = __shfl_xor((unsigned)(v >> 32), m);
  return ((u64)hi << 32) | lo;
}
// order-preserving float<->uint (handles negative d' = t - 2g)
__device__ __forceinline__ unsigned fenc(float f) {
  unsigned u = __float_as_uint(f);
  return (u & 0x80000000u) ? ~u : (u | 0x80000000u);
}
__device__ __forceinline__ float fdec(unsigned e) {
  return __uint_as_float((e & 0x80000000u) ? (e ^ 0x80000000u) : ~e);
}

// -----------------------------------------------------------------------------
// init (32768 threads): exact t_k (np-pairwise), zero hist/lacc, pack codebook
// bf16 hi/lo in MFMA B-fragment order (verified R2/R4/R5), w passthrough.
__global__ void vq_init(const float* __restrict__ w, float* __restrict__ ws,
                        float* __restrict__ dout) {
#pragma clang fp contract(off)
  int t = blockIdx.x * blockDim.x + threadIdx.x;
  if (t < KK) {
    const float* wr = w + t * DD;
    float r[8];
#pragma unroll
    for (int j = 0; j < 8; j++) { float v = wr[j]; r[j] = v * v; }
#pragma unroll
    for (int blk = 8; blk < 64; blk += 8) {
#pragma unroll
      for (int j = 0; j < 8; j++) { float v = wr[blk + j]; float a = v * v; r[j] = r[j] + a; }
    }
    ws[WS_TVEC + t] = ((r[0] + r[1]) + (r[2] + r[3])) + ((r[4] + r[5]) + (r[6] + r[7]));
    ((int*)ws)[WS_HIST + t] = 0;
  }
  if (t == 0) ws[WS_LACC] = 0.0f;

  // codebook pack: B elem (k,n) -> lane = n + 16*(k/8), j = k%8
  {
    int j    = t & 7;
    int lane = (t >> 3) & 63;
    int ks   = (t >> 9) & 1;
    int ct   = t >> 10;
    int code = ct * 16 + (lane & 15);
    int d    = ks * 32 + ((lane >> 4) << 3) + j;
    float v  = w[code * DD + d];
    unsigned short h = f2bf(v);
    unsigned short l = f2bf(v - bf2f(h));
    ((unsigned short*)(ws + WS_WPH))[((ct * 2 + ks) * 64 + lane) * 8 + j] = h;
    ((unsigned short*)(ws + WS_WPL))[((ct * 2 + ks) * 64 + lane) * 8 + j] = l;
  }

  // weight passthrough (W_OFF 8B-aligned -> float2)
  if (t < KK * DD / 2) {
    ((float2*)(dout + W_OFF))[t] = ((const float2*)w)[t];
  }
}

// -----------------------------------------------------------------------------
// main: 1024 blocks x 256 threads. Wave owns 64 rows (4 MFMA row-tiles), lane
// owns 1 row. Staging time-multiplexes ONE 32 KB buffer (hi pass then lo pass)
// so LDS = 40.4 KB -> 3-4 blocks/CU (was 73 KB / 2 blocks). s-less filter
// (d' = t - 2g, shift-invariant); exact bit-matching rescue. xr reload issued
// right after the loop so the butterfly/window phase hides its L3 latency.
__launch_bounds__(256, 2)
__global__ void vq_main(const float* __restrict__ x, const float* __restrict__ w,
                        const float* __restrict__ ws, float* __restrict__ dout) {
#pragma clang fp contract(off)
  __shared__ uint4 xs_lds[4][64][8];        // 32 KB, holds hi then lo (time-muxed)
  __shared__ float t_lds[KK];               // 2 KB
  __shared__ u64   g_lds[256];              // 2 KB
  __shared__ unsigned short cand[256][4];   // 2 KB
  __shared__ int   ccnt[256];               // 1 KB
  __shared__ unsigned char flags[KK];       // 512 B

  const float* tvec = ws + WS_TVEC;
  const s16x8* wph8 = (const s16x8*)(ws + WS_WPH);
  const s16x8* wpl8 = (const s16x8*)(ws + WS_WPL);
  int* hist = (int*)ws + WS_HIST;
  float* lacc = (float*)ws + WS_LACC;

  const int tid  = threadIdx.x;
  const int lane = tid & 63;
  const int wv   = tid >> 6;
  const int res  = lane & 15;       // code residue this lane tracks

  for (int e = tid; e < KK; e += 256) { t_lds[e] = tvec[e]; flags[e] = 0; }
  ccnt[tid] = 0;

  const int n = blockIdx.x * 256 + wv * 64 + lane;   // lane's row
  const int b = n >> 13, l = n & 8191;
  const float* px = x + (size_t)b * DD * LL + l;

  // ---- stage: hi pass, read afh; lo pass, read afl (one 32 KB buffer) ----
  s16x8 afh[4][2], afl[4][2];
  {
    float xv[64];
#pragma unroll
    for (int i = 0; i < 64; i++) xv[i] = px[(size_t)i * LL];

    // hi pass
#pragma unroll
    for (int blk = 0; blk < 8; blk++) {
      unsigned ph[4];
#pragma unroll
      for (int q = 0; q < 4; q++) {
        float v0 = xv[blk * 8 + 2 * q], v1 = xv[blk * 8 + 2 * q + 1];
        ph[q] = (unsigned)f2bf(v0) | ((unsigned)f2bf(v1) << 16);
      }
      int sw = blk ^ (lane & 7);          // swizzle (R5-verified; b128-floor conflicts)
      uint4 vh; vh.x = ph[0]; vh.y = ph[1]; vh.z = ph[2]; vh.w = ph[3];
      xs_lds[wv][lane][sw] = vh;
    }
    __syncthreads();   // barrier #1: t_lds/flags/ccnt + hi stage visible
    {
      const s16x8* xs8 = (const s16x8*)xs_lds;
#pragma unroll
      for (int t2 = 0; t2 < 4; t2++)
#pragma unroll
        for (int ks = 0; ks < 2; ks++) {
          int idx = (wv * 64 + t2 * 16 + (lane & 15)) * 8 + ((ks * 4 + (lane >> 4)) ^ (lane & 7));
          afh[t2][ks] = xs8[idx];
        }
    }
    __syncthreads();   // barrier #2: hi reads complete before lo overwrite

    // lo pass (residuals), same buffer
#pragma unroll
    for (int blk = 0; blk < 8; blk++) {
      unsigned pl[4];
#pragma unroll
      for (int q = 0; q < 4; q++) {
        float v0 = xv[blk * 8 + 2 * q],     h0f = bf2f(f2bf(v0));
        float v1 = xv[blk * 8 + 2 * q + 1], h1f = bf2f(f2bf(v1));
        pl[q] = (unsigned)f2bf(v0 - h0f) | ((unsigned)f2bf(v1 - h1f) << 16);
      }
      int sw = blk ^ (lane & 7);
      uint4 vl; vl.x = pl[0]; vl.y = pl[1]; vl.z = pl[2]; vl.w = pl[3];
      xs_lds[wv][lane][sw] = vl;
    }
    __syncthreads();   // barrier #3: lo staged
    {
      const s16x8* xs8 = (const s16x8*)xs_lds;
#pragma unroll
      for (int t2 = 0; t2 < 4; t2++)
#pragma unroll
        for (int ks = 0; ks < 2; ks++) {
          int idx = (wv * 64 + t2 * 16 + (lane & 15)) * 8 + ((ks * 4 + (lane >> 4)) ^ (lane & 7));
          afl[t2][ks] = xs8[idx];
        }
    }
  }   // xv dead here

  float d1[4][4], d2[4][4]; int k1[4][4];
#pragma unroll
  for (int t2 = 0; t2 < 4; t2++)
#pragma unroll
    for (int r = 0; r < 4; r++) { d1[t2][r] = INFINITY; d2[t2][r] = INFINITY; k1[t2][r] = 0; }

  // B prefetch (1-deep ring)
  s16x8 bh0 = wph8[lane], bh1 = wph8[64 + lane];
  s16x8 bl0 = wpl8[lane], bl1 = wpl8[64 + lane];
  float tc = t_lds[res];

#pragma clang loop unroll(disable)
  for (int ct = 0; ct < 32; ct++) {
    int cn = (ct + 1) & 31;   // wrap: harmless re-read
    s16x8 nh0 = wph8[cn * 128 + lane],      nh1 = wph8[cn * 128 + 64 + lane];
    s16x8 nl0 = wpl8[cn * 128 + lane],      nl1 = wpl8[cn * 128 + 64 + lane];
    float ntc = t_lds[cn * 16 + res];

#pragma unroll
    for (int t2 = 0; t2 < 4; t2++) {
      f32x4 acc = {0.f, 0.f, 0.f, 0.f};
      acc = __builtin_amdgcn_mfma_f32_16x16x32_bf16(afl[t2][0], bh0, acc, 0, 0, 0);
      acc = __builtin_amdgcn_mfma_f32_16x16x32_bf16(afl[t2][1], bh1, acc, 0, 0, 0);
      acc = __builtin_amdgcn_mfma_f32_16x16x32_bf16(afh[t2][0], bl0, acc, 0, 0, 0);
      acc = __builtin_amdgcn_mfma_f32_16x16x32_bf16(afh[t2][1], bl1, acc, 0, 0, 0);
      acc = __builtin_amdgcn_mfma_f32_16x16x32_bf16(afh[t2][0], bh0, acc, 0, 0, 0);
      acc = __builtin_amdgcn_mfma_f32_16x16x32_bf16(afh[t2][1], bh1, acc, 0, 0, 0);
#pragma unroll
      for (int r = 0; r < 4; r++) {
        float dap = fmaf(-2.0f, acc[r], tc);   // s-less: d' = t - 2g
        bool c1 = dap < d1[t2][r];
        bool c2 = dap < d2[t2][r];
        d2[t2][r] = c1 ? d1[t2][r] : (c2 ? dap : d2[t2][r]);
        d1[t2][r] = c1 ? dap : d1[t2][r];
        k1[t2][r] = c1 ? ct : k1[t2][r];
      }
    }
    bh0 = nh0; bh1 = nh1; bl0 = nl0; bl1 = nl1; tc = ntc;
  }

  // ---- issue exact-x reload NOW (pinned post-loop); butterfly hides latency ----
  __builtin_amdgcn_sched_barrier(0);
  float xr[64];
#pragma unroll
  for (int i = 0; i < 64; i++) xr[i] = px[(size_t)i * LL];

  // ---- per-row global min (order-preserving encode handles negative d') ----
  u64 gmin[4][4];
#pragma unroll
  for (int t2 = 0; t2 < 4; t2++)
#pragma unroll
    for (int r = 0; r < 4; r++) {
      u64 pk = (((u64)fenc(d1[t2][r])) << 32) | (u64)(k1[t2][r] * 16 + res);
      u64 q1 = shflx64(pk, 1); pk = pk < q1 ? pk : q1;
      u64 q2 = shflx64(pk, 2); pk = pk < q2 ? pk : q2;
      u64 q4 = shflx64(pk, 4); pk = pk < q4 ? pk : q4;
      u64 q8 = shflx64(pk, 8); pk = pk < q8 ? pk : q8;
      gmin[t2][r] = pk;
    }

  // window collection (rows wave-owned; LDS atomics)
#pragma unroll
  for (int t2 = 0; t2 < 4; t2++)
#pragma unroll
    for (int r = 0; r < 4; r++) {
      int row = wv * 64 + t2 * 16 + ((lane >> 4) << 2) + r;
      if (res == 0) g_lds[row] = gmin[t2][r];
      float thr = fdec((unsigned)(gmin[t2][r] >> 32)) + WINDOW;
      bool in1 = d1[t2][r] <= thr;
      bool in2 = d2[t2][r] <= thr;
      if (in1) { int p = atomicAdd(&ccnt[row], 1); if (p < 4) cand[row][p] = (unsigned short)(k1[t2][r] * 16 + res); }
      if (in2) { int p = atomicAdd(&ccnt[row], 1); if (p < 4) cand[row][p] = (unsigned short)(512 + res); }
    }
  __syncthreads();   // barrier #4: collection visible

  // ---- owner decision (every lane owns its row) ----
  int kwin;
  {
    int row = wv * 64 + lane;
    int cnt = ccnt[row];
    if (cnt <= 1) {
      kwin = (int)(g_lds[row] & 0x1FFu);
    } else {
      // exact rescue: bit-identical chains to reference
      float s;
      {
        float r[8];
#pragma unroll
        for (int j = 0; j < 8; j++) r[j] = xr[j] * xr[j];
#pragma unroll
        for (int blk = 8; blk < 64; blk += 8)
#pragma unroll
          for (int j = 0; j < 8; j++) { float a = xr[blk + j] * xr[blk + j]; r[j] = r[j] + a; }
        s = ((r[0] + r[1]) + (r[2] + r[3])) + ((r[4] + r[5]) + (r[6] + r[7]));
      }
      u64 best = ~0ULL;
      auto evalExact = [&](int c) {
        const float4* wr = (const float4*)(w + c * DD);
        float gg = 0.0f;
#pragma unroll
        for (int i = 0; i < 16; i++) {
          float4 wq = wr[i];
          gg = fmaf(xr[4 * i + 0], wq.x, gg); gg = fmaf(xr[4 * i + 1], wq.y, gg);
          gg = fmaf(xr[4 * i + 2], wq.z, gg); gg = fmaf(xr[4 * i + 3], wq.w, gg);
        }
        float de = fmaf(-2.0f, gg, s + t_lds[c]);   // ref chain: fl(s+t) then fma
        u64 pk = (((u64)__float_as_uint(de)) << 32) | (u64)c;   // de>0: bit order ok
        if (pk < best) best = pk;
      };
      if (cnt > 4) {
        for (int c = 0; c < KK; c++) evalExact(c);
      } else {
        for (int i = 0; i < cnt; i++) {
          int c = cand[row][i];
          if (c < 512) evalExact(c);
          else { int c0 = c - 512; for (int jj = 0; jj < 32; jj++) evalExact(jj * 16 + c0); }
        }
      }
      kwin = (int)(best & 0x1FFu);   // masked: logic bug => wrong answer, never OOB
    }
  }

  // ---- epilogue: quantized output (transposed back), loss partial, idx, flags ----
  float ls = 0.0f;
  {
    float* o = dout + (size_t)b * DD * LL + l;
    const float4* wr = (const float4*)(w + kwin * DD);
#pragma unroll
    for (int i = 0; i < 16; i++) {
      float4 v = wr[i];
      o[(size_t)(4 * i + 0) * LL] = v.x; o[(size_t)(4 * i + 1) * LL] = v.y;
      o[(size_t)(4 * i + 2) * LL] = v.z; o[(size_t)(4 * i + 3) * LL] = v.w;
      float df;
      df = v.x - xr[4 * i + 0]; ls = fmaf(df, df, ls);
      df = v.y - xr[4 * i + 1]; ls = fmaf(df, df, ls);
      df = v.z - xr[4 * i + 2]; ls = fmaf(df, df, ls);
      df = v.w - xr[4 * i + 3]; ls = fmaf(df, df, ls);
    }
  }
  dout[IDX_OFF + n] = (float)kwin;
  flags[kwin] = 1;   // byte races benign (same value)

  // loss: wave reduce then one atomic per wave (order-insensitive at tolerance)
#pragma unroll
  for (int o = 32; o > 0; o >>= 1) ls += __shfl_down(ls, o);
  if ((tid & 63) == 0) atomicAdd(lacc, ls);

  __syncthreads();   // barrier #5: flags complete
  for (int e = tid; e < KK; e += 256)
    if (flags[e]) atomicOr(&hist[e], 1);
}

// -----------------------------------------------------------------------------
// final: perplexity count + loss scalar (w passthrough in vq_init)
__global__ void vq_final(const float* __restrict__ ws, float* __restrict__ dout) {
  __shared__ int red[512];
  const int* hist = (const int*)ws + WS_HIST;
  int tid = threadIdx.x;
  red[tid] = (hist[tid] != 0) ? 1 : 0;
  __syncthreads();
  for (int sx = 256; sx > 0; sx >>= 1) {
    if (tid < sx) red[tid] += red[tid + sx];
    __syncthreads();
  }
  if (tid == 0) {
    dout[PERP_OFF] = (float)red[0];
    float m = ws[WS_LACC] / 16777216.0f;
    dout[LOSS_OFF] = m + 0.1f * m;   // q + 0.1*e with q==e numerically
  }
}

extern "C" void kernel_launch(void* const* d_in, const int* in_sizes, int n_in,
                              void* d_out, int out_size, void* d_ws, size_t ws_size,
                              hipStream_t stream) {
  const float* x = (const float*)d_in[0];
  const float* w = (const float*)d_in[1];
  float* dout = (float*)d_out;
  float* ws = (float*)d_ws;

  vq_init<<<128, 256, 0, stream>>>(w, ws, dout);
  vq_main<<<NN / 256, 256, 0, stream>>>(x, w, ws, dout);
  vq_final<<<1, 512, 0, stream>>>(ws, dout);
}